// Round 2
// baseline (1251.805 us; speedup 1.0000x reference)
//
#include <hip/hip_runtime.h>
#include <cmath>

// ---------------- problem constants ----------------
constexpr int cB = 16;
constexpr int cN = 4096;
constexpr int cC = 256;

// ---------------- workspace layout (float offsets) — total 40,838,144 floats = 163.4 MB ----------------
constexpr size_t oWQT    = 0;                                   // 256x256
constexpr size_t oW1T    = oWQT    + (size_t)256*256;           // 4096x256
constexpr size_t oW2T    = oW1T    + (size_t)4096*256;          // 1024x256
constexpr size_t oWKV1T  = oW2T    + (size_t)1024*256;          // 256x512
constexpr size_t oWKV2T  = oWKV1T  + (size_t)256*512;           // 256x512
constexpr size_t oWPROJT = oWKV2T  + (size_t)256*512;           // 512x256
constexpr size_t oINVSP  = oWPROJT + (size_t)512*256;           // 256 (pad 1024)
constexpr size_t oKM1    = oINVSP  + 1024;                      // B*8*32
constexpr size_t oKV1M   = oKM1    + (size_t)cB*8*32;           // B*8*1024
constexpr size_t oKM2    = oKV1M   + (size_t)cB*8*1024;         // B*8*32
constexpr size_t oKV2M   = oKM2    + (size_t)cB*8*32;           // B*8*1024
constexpr size_t oQBUF   = oKV2M   + (size_t)cB*8*1024;         // B*N*C   q (scattered layout)
constexpr size_t oV1G    = oQBUF   + (size_t)cB*cN*cC;          // B*256*256
constexpr size_t oV2G    = oV1G    + (size_t)cB*256*256;        // B*1024*256
constexpr size_t oU      = oV2G    + (size_t)cB*1024*256;       // 16,777,216-float union region
// Inside U (time-multiplexed):
constexpr size_t oX1     = oU;                                  // B*256*256   (phase 1)
constexpr size_t oY1     = oX1 + (size_t)cB*256*256;            // B*256*512   (phase 1)
constexpr size_t oK1P    = oY1 + (size_t)cB*256*512;            // B*256*256   (phase 1)
constexpr size_t oX2     = oU;                                  // B*1024*256  (phase 2)
constexpr size_t oY2     = oX2 + (size_t)cB*1024*256;           // B*1024*512  (phase 2)
constexpr size_t oK2P    = oY2 + (size_t)cB*1024*512;           // B*1024*256  (phase 2)
constexpr size_t oA      = oU;                                  // B*N*C       (phase 3, per-branch attn out)
constexpr size_t oEND    = oU + (size_t)cB*cN*cC;

// ---------------- small repacks ----------------
__global__ void transpose_mn(const float* __restrict__ src, float* __restrict__ dst, int M, int N) {
  int idx = blockIdx.x*256 + threadIdx.x;
  if (idx >= M*N) return;
  int m = idx / N, n = idx - m*N;
  dst[(size_t)n*M + m] = src[idx];
}

// Wsr (co=256, ci=256, kh, kw) -> dst[(p*256+ci)*256 + co],  p = ky*kw+kx (flat)
__global__ void repack_conv_w(const float* __restrict__ src, float* __restrict__ dst, int KHW) {
  int idx = blockIdx.x*256 + threadIdx.x;
  if (idx >= 256*256*KHW) return;
  int co = idx & 255;
  int k  = idx >> 8;
  int ci = k & 255;
  int p  = k >> 8;
  dst[idx] = src[((size_t)co*256 + ci)*KHW + p];
}

__global__ void softplus_inv_k(const float* __restrict__ s, float* __restrict__ inv) {
  int c = threadIdx.x;
  float v = s[c];
  float sp = (v > 20.f) ? v : log1pf(expf(v));
  inv[c] = 1.f/sp;
}

// ---------------- generic f32 GEMM, 64x64 tile, 256 threads ----------------
// AMODE: 0 = A row-major (lda=K); 1 = conv1 patch gather (K=4096); 2 = conv2 patch gather (K=1024)
// EPI:   0 = C[r*N+c] = acc+bias[c]; 1 = q-scatter epilogue (+bias); 2 = C[r*N+c] += acc (no bias)
template<int AMODE, int EPI>
__global__ __launch_bounds__(256) void gemm64(
    const float* __restrict__ A, const float* __restrict__ Bt,
    const float* __restrict__ bias, float* __restrict__ Cout,
    int M, int N, int K)
{
  __shared__ float As[32][68];
  __shared__ float Bs[32][68];
  const int tid  = threadIdx.x;
  const int row0 = blockIdx.x * 64;
  const int col0 = blockIdx.y * 64;
  const int tx = tid & 15, ty = tid >> 4;
  float acc[4][4] = {};

  for (int k0 = 0; k0 < K; k0 += 32) {
    // A tile: 64 rows x 32 k
    #pragma unroll
    for (int i = 0; i < 2; ++i) {
      int f = tid + i*256;            // 0..511
      int m = f >> 3, kq = f & 7;     // m 0..63, kq 0..7 (4 floats each)
      int r = row0 + m;
      const float* ap;
      if (AMODE == 0) {
        ap = A + (size_t)r*K + k0 + kq*4;
      } else if (AMODE == 1) {
        int b = r >> 8, mm = r & 255;
        int my = mm >> 4, mx = mm & 15;
        int chunk = k0 >> 8;                 // = ky*4+kx
        int ky = chunk >> 2, kx = chunk & 3;
        int tok = (4*my + ky)*64 + 4*mx + kx;
        ap = A + ((size_t)(b*4096 + tok))*256 + (k0 & 255) + kq*4;
      } else {
        int b = r >> 10, mm = r & 1023;
        int my = mm >> 5, mx = mm & 31;
        int chunk = k0 >> 8;                 // = ky*2+kx
        int ky = chunk >> 1, kx = chunk & 1;
        int tok = (2*my + ky)*64 + 2*mx + kx;
        ap = A + ((size_t)(b*4096 + tok))*256 + (k0 & 255) + kq*4;
      }
      float4 v = *(const float4*)ap;
      As[kq*4+0][m] = v.x;
      As[kq*4+1][m] = v.y;
      As[kq*4+2][m] = v.z;
      As[kq*4+3][m] = v.w;
    }
    // B tile: 32 k x 64 cols
    #pragma unroll
    for (int i = 0; i < 2; ++i) {
      int f = tid + i*256;
      int kk = f >> 4, cq = f & 15;
      float4 v = *(const float4*)(Bt + (size_t)(k0 + kk)*N + col0 + cq*4);
      *(float4*)&Bs[kk][cq*4] = v;
    }
    __syncthreads();
    #pragma unroll
    for (int kk = 0; kk < 32; ++kk) {
      float4 a4 = *(const float4*)&As[kk][ty*4];
      float4 b4 = *(const float4*)&Bs[kk][tx*4];
      float av[4] = {a4.x, a4.y, a4.z, a4.w};
      float bv[4] = {b4.x, b4.y, b4.z, b4.w};
      #pragma unroll
      for (int i2 = 0; i2 < 4; ++i2)
        #pragma unroll
        for (int j = 0; j < 4; ++j)
          acc[i2][j] += av[i2]*bv[j];
    }
    __syncthreads();
  }

  #pragma unroll
  for (int i2 = 0; i2 < 4; ++i2) {
    int r = row0 + ty*4 + i2;
    int c = col0 + tx*4;
    float4 val;
    val.x = acc[i2][0]; val.y = acc[i2][1]; val.z = acc[i2][2]; val.w = acc[i2][3];
    if (EPI != 2) {
      float4 bv = *(const float4*)(bias + c);
      val.x += bv.x; val.y += bv.y; val.z += bv.z; val.w += bv.w;
    }
    if (EPI == 0) {
      *(float4*)(Cout + (size_t)r*N + c) = val;
    } else if (EPI == 1) {
      // q scatter: qpre[b,n,h*32+d] -> q_lin[b, h*512+(n>>3), (n&7)*32+d]
      int b = r >> 12, n = r & 4095;
      int h = c >> 5, d = c & 31;
      size_t o = ((size_t)(b*4096 + h*512 + (n >> 3)))*256 + (n & 7)*32 + d;
      *(float4*)(Cout + o) = val;
    } else {
      float* p = Cout + (size_t)r*N + c;
      float4 prev = *(float4*)p;
      val.x += prev.x; val.y += prev.y; val.z += prev.z; val.w += prev.w;
      *(float4*)p = val;
    }
  }
}

// ---------------- row-wise focused-linear-attention nonlinearity ----------------
__global__ __launch_bounds__(256) void row_powernorm(float* __restrict__ x,
    const float* __restrict__ inv_sp, int rows)
{
  int row = blockIdx.x*4 + (threadIdx.x >> 6);
  if (row >= rows) return;
  int lane = threadIdx.x & 63;
  float* p = x + (size_t)row*256 + lane*4;
  float4 v = *(float4*)p;
  const float4 is = *(const float4*)(inv_sp + lane*4);
  float r0 = (fmaxf(v.x,0.f)+1e-6f)*is.x;
  float r1 = (fmaxf(v.y,0.f)+1e-6f)*is.y;
  float r2 = (fmaxf(v.z,0.f)+1e-6f)*is.z;
  float r3 = (fmaxf(v.w,0.f)+1e-6f)*is.w;
  float s2 = r0*r0+r1*r1+r2*r2+r3*r3;
  #pragma unroll
  for (int o = 1; o < 64; o <<= 1) s2 += __shfl_xor(s2, o, 64);
  float c0 = r0*r0*r0, c1 = r1*r1*r1, c2 = r2*r2*r2, c3 = r3*r3*r3;
  float s6 = c0*c0+c1*c1+c2*c2+c3*c3;
  #pragma unroll
  for (int o = 1; o < 64; o <<= 1) s6 += __shfl_xor(s6, o, 64);
  float f = sqrtf(s2/s6);
  v.x = c0*f; v.y = c1*f; v.z = c2*f; v.w = c3*f;
  *(float4*)p = v;
}

// ---------------- LayerNorm + exact GELU, in-place on 256-wide rows ----------------
__global__ __launch_bounds__(256) void ln_gelu(float* __restrict__ x,
    const float* __restrict__ g, const float* __restrict__ bb, int rows)
{
  int row = blockIdx.x*4 + (threadIdx.x >> 6);
  if (row >= rows) return;
  int lane = threadIdx.x & 63;
  float* p = x + (size_t)row*256 + lane*4;
  float4 v = *(float4*)p;
  float s = v.x+v.y+v.z+v.w;
  #pragma unroll
  for (int o = 1; o < 64; o <<= 1) s += __shfl_xor(s, o, 64);
  float mu = s*(1.f/256.f);
  float d0 = v.x-mu, d1 = v.y-mu, d2 = v.z-mu, d3 = v.w-mu;
  float q = d0*d0+d1*d1+d2*d2+d3*d3;
  #pragma unroll
  for (int o = 1; o < 64; o <<= 1) q += __shfl_xor(q, o, 64);
  float rstd = rsqrtf(q*(1.f/256.f) + 1e-5f);
  float4 gv = *(const float4*)(g + lane*4);
  float4 bv = *(const float4*)(bb + lane*4);
  float y0 = d0*rstd*gv.x + bv.x;
  float y1 = d1*rstd*gv.y + bv.y;
  float y2 = d2*rstd*gv.z + bv.z;
  float y3 = d3*rstd*gv.w + bv.w;
  const float k = 0.70710678118654752f;
  v.x = 0.5f*y0*(1.f+erff(y0*k));
  v.y = 0.5f*y1*(1.f+erff(y1*k));
  v.z = 0.5f*y2*(1.f+erff(y2*k));
  v.w = 0.5f*y3*(1.f+erff(y3*k));
  *(float4*)p = v;
}

// ---------------- k/v gather (transpose-scramble of y_raw) via LDS tile ----------------
template<int BR, int ISV>
__global__ __launch_bounds__(256) void gather_kv(const float* __restrict__ y,
    const float* __restrict__ pe, float* __restrict__ out)
{
  constexpr int NKV = (BR == 1) ? 256 : 1024;
  __shared__ float tile[64][65];
  int bid = blockIdx.x;
  int cb = bid & 3;
  int nb = (bid >> 2) % (NKV/64);
  int b  = (bid >> 2) / (NKV/64);
  int n0 = nb*64, c0 = cb*64;
  int tid = threadIdx.x;
  #pragma unroll
  for (int pass = 0; pass < 16; ++pass) {
    int c_l = (tid >> 6)*16 + pass;  // 0..63
    int c = c0 + c_l;
    int n_l;
    size_t addr;
    if (BR == 1) {
      n_l = tid & 63;
      addr = ((size_t)(b*256 + c))*512 + 2*(n0 + n_l) + ISV;
    } else {
      int u = tid & 31, pp = (tid >> 5) & 1;
      n_l = 2*u + pp;
      addr = ((size_t)(b*1024 + pp*512 + ISV*256 + c))*512 + (size_t)((n0 >> 1) + u);
    }
    tile[c_l][n_l] = y[addr];
  }
  __syncthreads();
  #pragma unroll
  for (int pass = 0; pass < 16; ++pass) {
    int n_l = (tid >> 6)*16 + pass;
    int c_l = tid & 63;
    int n = n0 + n_l, c = c0 + c_l;
    float v = tile[c_l][n_l];
    if (ISV == 0) v += pe[n*256 + c];
    out[((size_t)(b*NKV + n))*256 + c] = v;
  }
}

// ---------------- per (b,h): km = mean_n k ; kv = (1/4096) * K^T V ----------------
__global__ __launch_bounds__(256) void kmkv(const float* __restrict__ kp,
    const float* __restrict__ vg, float* __restrict__ km, float* __restrict__ kvm, int nkv)
{
  int b = blockIdx.x >> 3, h = blockIdx.x & 7;
  int tid = threadIdx.x;
  __shared__ float ks[64][32];
  __shared__ float vs[64][32];
  int d  = tid >> 3;
  int e0 = (tid & 7)*4;
  float acc[4] = {0.f,0.f,0.f,0.f};
  float kmacc = 0.f;
  for (int n0 = 0; n0 < nkv; n0 += 64) {
    #pragma unroll
    for (int i = 0; i < 2; ++i) {
      int f = tid + i*256;
      int nn = f >> 3, q4 = (f & 7)*4;
      size_t base = ((size_t)(b*nkv + n0 + nn))*256 + h*32 + q4;
      *(float4*)&ks[nn][q4] = *(const float4*)(kp + base);
      *(float4*)&vs[nn][q4] = *(const float4*)(vg + base);
    }
    __syncthreads();
    #pragma unroll 8
    for (int nn = 0; nn < 64; ++nn) {
      float kd = ks[nn][d];
      kmacc += kd;
      #pragma unroll
      for (int j = 0; j < 4; ++j) acc[j] += kd * vs[nn][e0+j];
    }
    __syncthreads();
  }
  const float s2 = 1.0f/4096.0f;
  #pragma unroll
  for (int j = 0; j < 4; ++j)
    kvm[(((size_t)(b*8 + h))*32 + d)*32 + e0 + j] = acc[j]*s2;
  if ((tid & 7) == 0) km[(b*8 + h)*32 + d] = kmacc / (float)nkv;
}

// ---------------- single-branch attention matvec -> A (b,t,256) ----------------
__global__ __launch_bounds__(256) void attn_single(const float* __restrict__ q,
    const float* __restrict__ km, const float* __restrict__ kv, float* __restrict__ A)
{
  __shared__ float kvs[8*1057];   // per-head stride 1057, row stride 33 (conflict-free)
  __shared__ float kms[8*33];
  int b  = blockIdx.x >> 7;
  int t0 = (blockIdx.x & 127)*32;
  int tid = threadIdx.x;
  int h = tid & 7, tl = tid >> 3;
  int t = t0 + tl;
  for (int i = tid; i < 8*1024; i += 256) {
    int hh = i >> 10, de = i & 1023;
    kvs[hh*1057 + (de >> 5)*33 + (de & 31)] = kv[((size_t)(b*8 + hh))*1024 + de];
  }
  kms[(tid >> 5)*33 + (tid & 31)] = km[(size_t)b*256 + tid];
  float qreg[32];
  #pragma unroll
  for (int j = 0; j < 8; ++j) {
    float4 v = *(const float4*)(q + ((size_t)(b*4096 + t))*256 + h*32 + j*4);
    qreg[4*j+0] = v.x; qreg[4*j+1] = v.y; qreg[4*j+2] = v.z; qreg[4*j+3] = v.w;
  }
  __syncthreads();
  float dot = 0.f;
  #pragma unroll
  for (int d = 0; d < 32; ++d) dot += qreg[d]*kms[h*33 + d];
  float z = 1.0f/(dot + 1e-6f);
  float acc[32] = {};
  const float* kvp = &kvs[h*1057];
  #pragma unroll
  for (int d = 0; d < 32; ++d) {
    float qd = qreg[d];
    #pragma unroll
    for (int e = 0; e < 32; ++e) acc[e] += qd * kvp[d*33 + e];
  }
  float* outp = A + ((size_t)(b*4096 + t))*256 + h*32;
  #pragma unroll
  for (int j = 0; j < 8; ++j) {
    float4 v;
    v.x = acc[4*j+0]*z; v.y = acc[4*j+1]*z;
    v.z = acc[4*j+2]*z; v.w = acc[4*j+3]*z;
    *(float4*)(outp + 4*j) = v;
  }
}

// ---------------- fused interp + 5x5 depthwise conv (pad 2), += into A ----------------
// image(b,e,d,y,x) = v2[b, t=e*512+y*8+(x>>3), c=(x&7)*32+d], v2 = lerp of vr rows i0(t),i1(t)
// vr[b,r,c] = vg[b, (r%(L/8))*8 + (c>>5), (r/(L/8))*32 + (c&31)]
template<int BR>
__global__ __launch_bounds__(256) void dwconv_fused(const float* __restrict__ vg,
    const float* __restrict__ Wd, const float* __restrict__ bias, float* __restrict__ A)
{
  constexpr int L    = (BR == 1) ? 256 : 1024;
  constexpr int RPSH = (BR == 1) ? 5 : 7;       // log2(L/8)
  int bid = blockIdx.x;            // (b*8 + e)*64 + y
  int y = bid & 63; bid >>= 6;
  int e = bid & 7;
  int b = bid >> 3;
  int tid = threadIdx.x;
  int d = tid & 31, xg = tid >> 5; // xg 0..7 -> x = xg*8 + j
  float w[25];
  #pragma unroll
  for (int i = 0; i < 25; ++i) w[i] = Wd[d*25 + i];
  float acc[8] = {};
  #pragma unroll
  for (int dy = 0; dy < 5; ++dy) {
    int yy = y + dy - 2;
    if (yy >= 0 && yy <= 63) {
      float in[12];
      #pragma unroll
      for (int i = 0; i < 12; ++i) {
        int xx = xg*8 - 2 + i;
        if (xx < 0 || xx > 63) { in[i] = 0.f; }
        else {
          int t = e*512 + yy*8 + (xx >> 3);
          float cpos = ((float)t + 0.5f) * ((float)L / 4096.0f) - 0.5f;
          cpos = fminf(fmaxf(cpos, 0.0f), (float)(L-1));
          int i0 = (int)cpos;
          float wt = cpos - (float)i0;
          int i1 = (i0 + 1 < L) ? i0 + 1 : L - 1;
          int xl = xx & 7;
          int n0 = ((i0 & ((L/8)-1)) << 3) + xl, ch0 = ((i0 >> RPSH) << 5) + d;
          int n1 = ((i1 & ((L/8)-1)) << 3) + xl, ch1 = ((i1 >> RPSH) << 5) + d;
          float v0 = vg[((size_t)(b*L + n0))*256 + ch0];
          float v1 = vg[((size_t)(b*L + n1))*256 + ch1];
          in[i] = v0 + (v1 - v0)*wt;
        }
      }
      #pragma unroll
      for (int dx = 0; dx < 5; ++dx) {
        float ww = w[dy*5 + dx];
        #pragma unroll
        for (int j = 0; j < 8; ++j) acc[j] += ww * in[j + dx];
      }
    }
  }
  float bv = bias[d];
  #pragma unroll
  for (int j = 0; j < 8; ++j) {
    size_t o = ((size_t)(b*4096 + y*64 + xg*8 + j))*256 + e*32 + d;
    A[o] += acc[j] + bv;
  }
}

// ---------------- launcher ----------------
extern "C" void kernel_launch(void* const* d_in, const int* in_sizes, int n_in,
                              void* d_out, int out_size, void* d_ws, size_t ws_size,
                              hipStream_t stream)
{
  (void)in_sizes; (void)n_in; (void)out_size; (void)ws_size;
  const float* x     = (const float*)d_in[0];
  const float* Wq    = (const float*)d_in[1];
  const float* bq    = (const float*)d_in[2];
  const float* Wsr1  = (const float*)d_in[3];
  const float* bsr1  = (const float*)d_in[4];
  const float* g1    = (const float*)d_in[5];
  const float* b1    = (const float*)d_in[6];
  const float* Wsr2  = (const float*)d_in[7];
  const float* bsr2  = (const float*)d_in[8];
  const float* g2    = (const float*)d_in[9];
  const float* b2    = (const float*)d_in[10];
  const float* Wkv1  = (const float*)d_in[11];
  const float* bkv1  = (const float*)d_in[12];
  const float* Wkv2  = (const float*)d_in[13];
  const float* bkv2  = (const float*)d_in[14];
  const float* pe1   = (const float*)d_in[15];
  const float* pe2   = (const float*)d_in[16];
  const float* Wproj = (const float*)d_in[17];
  const float* bproj = (const float*)d_in[18];
  const float* Wdwc  = (const float*)d_in[19];
  const float* bdwc  = (const float*)d_in[20];
  const float* scale = (const float*)d_in[21];
  float* out = (float*)d_out;
  float* ws  = (float*)d_ws;
  dim3 blk(256);

  // weight repacks
  transpose_mn<<<256,  blk, 0, stream>>>(Wq,    ws+oWQT,    256, 256);
  repack_conv_w<<<4096, blk, 0, stream>>>(Wsr1, ws+oW1T, 16);
  repack_conv_w<<<1024, blk, 0, stream>>>(Wsr2, ws+oW2T, 4);
  transpose_mn<<<512,  blk, 0, stream>>>(Wkv1,  ws+oWKV1T,  512, 256);
  transpose_mn<<<512,  blk, 0, stream>>>(Wkv2,  ws+oWKV2T,  512, 256);
  transpose_mn<<<512,  blk, 0, stream>>>(Wproj, ws+oWPROJT, 256, 512);
  softplus_inv_k<<<1,  blk, 0, stream>>>(scale, ws+oINVSP);

  // q = x@Wq^T + bq, scattered to q_lin layout, then power-norm rows
  gemm64<0,1><<<dim3(1024,4), blk, 0, stream>>>(x, ws+oWQT, bq, ws+oQBUF, 65536, 256, 256);
  row_powernorm<<<16384, blk, 0, stream>>>(ws+oQBUF, ws+oINVSP, 65536);

  // ---- branch 1 staging (uses U: X1,Y1,K1P) ----
  gemm64<1,0><<<dim3(64,4),  blk, 0, stream>>>(x, ws+oW1T, bsr1, ws+oX1, 4096, 256, 4096);
  ln_gelu<<<1024, blk, 0, stream>>>(ws+oX1, g1, b1, 4096);
  gemm64<0,0><<<dim3(64,8),  blk, 0, stream>>>(ws+oX1, ws+oWKV1T, bkv1, ws+oY1, 4096,  512, 256);
  gather_kv<1,0><<<256,  blk, 0, stream>>>(ws+oY1, pe1, ws+oK1P);
  gather_kv<1,1><<<256,  blk, 0, stream>>>(ws+oY1, pe1, ws+oV1G);
  row_powernorm<<<1024, blk, 0, stream>>>(ws+oK1P, ws+oINVSP, 4096);
  kmkv<<<128, blk, 0, stream>>>(ws+oK1P, ws+oV1G, ws+oKM1, ws+oKV1M, 256);

  // ---- branch 2 staging (reuses U: X2,Y2,K2P) ----
  gemm64<2,0><<<dim3(256,4), blk, 0, stream>>>(x, ws+oW2T, bsr2, ws+oX2, 16384, 256, 1024);
  ln_gelu<<<4096, blk, 0, stream>>>(ws+oX2, g2, b2, 16384);
  gemm64<0,0><<<dim3(256,8), blk, 0, stream>>>(ws+oX2, ws+oWKV2T, bkv2, ws+oY2, 16384, 512, 256);
  gather_kv<2,0><<<1024, blk, 0, stream>>>(ws+oY2, pe2, ws+oK2P);
  gather_kv<2,1><<<1024, blk, 0, stream>>>(ws+oY2, pe2, ws+oV2G);
  row_powernorm<<<4096, blk, 0, stream>>>(ws+oK2P, ws+oINVSP, 16384);
  kmkv<<<128, blk, 0, stream>>>(ws+oK2P, ws+oV2G, ws+oKM2, ws+oKV2M, 1024);

  // ---- branch 1 output path (A reuses U) ----
  attn_single<<<cB*128, blk, 0, stream>>>(ws+oQBUF, ws+oKM1, ws+oKV1M, ws+oA);
  dwconv_fused<1><<<cB*8*64, blk, 0, stream>>>(ws+oV1G, Wdwc, bdwc, ws+oA);
  gemm64<0,0><<<dim3(1024,4), blk, 0, stream>>>(ws+oA, ws+oWPROJT, bproj, out, 65536, 256, 256);

  // ---- branch 2 output path ----
  attn_single<<<cB*128, blk, 0, stream>>>(ws+oQBUF, ws+oKM2, ws+oKV2M, ws+oA);
  dwconv_fused<2><<<cB*8*64, blk, 0, stream>>>(ws+oV2G, Wdwc, bdwc, ws+oA);
  gemm64<0,2><<<dim3(1024,4), blk, 0, stream>>>(ws+oA, ws+oWPROJT + (size_t)256*256, bproj, out, 65536, 256, 256);
}

// Round 3
// 680.065 us; speedup vs baseline: 1.8407x; 1.8407x over previous
//
#include <hip/hip_runtime.h>
#include <hip/hip_bf16.h>
#include <cmath>

// ---------------- problem constants ----------------
constexpr int cB = 16;
constexpr int cN = 4096;
constexpr int cC = 256;

typedef __attribute__((ext_vector_type(8))) short short8;
typedef __attribute__((ext_vector_type(4))) float f32x4;

__device__ inline unsigned short bfr(float f) {
  __hip_bfloat16 h = __float2bfloat16(f);
  return *(unsigned short*)&h;
}
__device__ inline float bf2f(unsigned short u) {
  unsigned int v = ((unsigned int)u) << 16;
  return *(float*)&v;
}

// ---------------- workspace layout (float units) — total 37,856,256 floats = 151.4 MB ----------------
constexpr size_t oWQB    = 0;                               // 256x256 bf16
constexpr size_t oW1B    = oWQB    + 32768;                 // 256x4096 bf16
constexpr size_t oW2B    = oW1B    + 524288;                // 256x1024 bf16
constexpr size_t oWKV1B  = oW2B    + 131072;                // 512x256 bf16
constexpr size_t oWKV2B  = oWKV1B  + 65536;                 // 512x256 bf16
constexpr size_t oWPROJB = oWKV2B  + 65536;                 // 256x512 bf16
constexpr size_t oINVSP  = oWPROJB + 65536;                 // 256 f32 (pad 1024)
constexpr size_t oKM1    = oINVSP  + 1024;                  // 16*8*32 f32
constexpr size_t oKV1M   = oKM1    + 4096;                  // 16*8*1024 f32
constexpr size_t oKM2    = oKV1M   + 131072;
constexpr size_t oKV2M   = oKM2    + 4096;
constexpr size_t oQBUF   = oKV2M   + 131072;                // B*N*C f32 (scattered q layout)
constexpr size_t oV1G    = oQBUF   + 16777216;              // B*256*256 f32
constexpr size_t oV2G    = oV1G    + 1048576;               // B*1024*256 f32
constexpr size_t oU      = oV2G    + 4194304;               // union region, 14,680,064 f32
// phase 1 (branch-1 staging):
constexpr size_t oX1     = oU;                              // B*256*256 f32
constexpr size_t oY1     = oU  + 1048576;                   // B*256*512 f32
constexpr size_t oX1B    = oU  + 3145728;                   // B*256*256 bf16 (524288 f32)
constexpr size_t oK1P    = oU;                              // aliases X1 (dead)
// phase 2 (branch-2 staging):
constexpr size_t oX2     = oU;                              // B*1024*256 f32
constexpr size_t oY2     = oU  + 4194304;                   // B*1024*512 f32
constexpr size_t oX2B    = oU  + 12582912;                  // B*1024*256 bf16 (2097152 f32)
constexpr size_t oK2P    = oU;                              // aliases X2 (dead)
// phase 3 (per-branch output):
constexpr size_t oAB     = oU;                              // B*N*C bf16 (8388608 f32)

// ---------------- weight packs (all B matrices become [N][K] bf16 row-major) ----------------
__global__ void cast_bf16_k(const float* __restrict__ src, __hip_bfloat16* __restrict__ dst, int n) {
  int idx = blockIdx.x*256 + threadIdx.x;
  if (idx < n) dst[idx] = __float2bfloat16(src[idx]);
}

// Wsr (co,ci,kh,kw) -> dst[co][p*256+ci] bf16, p = ky*kw+kx flat
__global__ void pack_conv_bf16(const float* __restrict__ src, __hip_bfloat16* __restrict__ dst, int KHW) {
  int idx = blockIdx.x*256 + threadIdx.x;   // over 65536*KHW, = ((co*KHW+p)*256+ci)
  if (idx >= 65536*KHW) return;
  int ci = idx & 255;
  int rest = idx >> 8;
  int p = rest % KHW, co = rest / KHW;
  dst[idx] = __float2bfloat16(src[((size_t)co*256 + ci)*KHW + p]);
}

__global__ void softplus_inv_k(const float* __restrict__ s, float* __restrict__ inv) {
  int c = threadIdx.x;
  float v = s[c];
  float sp = (v > 20.f) ? v : log1pf(expf(v));
  inv[c] = 1.f/sp;
}

// ---------------- MFMA bf16 GEMM ----------------
// TM,TN tile; AMODE: 0 = row-major A (lda=K); 1/2 = conv1/conv2 patch gather (f32 src)
// ADT: 0 = f32 A source (convert on the fly), 1 = bf16 A source
// EPI: 0 = C=acc+bias; 1 = q-scatter (+bias); 2 = C+=acc (no bias)
template<int TM, int TN, int AMODE, int ADT, int EPI>
__global__ __launch_bounds__(256) void gmfma(
    const void* __restrict__ Asrc, const __hip_bfloat16* __restrict__ Bp,
    const float* __restrict__ bias, float* __restrict__ Cout,
    int M, int N, int K, int ldb)
{
  constexpr int APASS = TM/32, BPASS = TN/32;
  constexpr int WGM = (TM==128) ? 2 : ((TN==64) ? 2 : 1);
  constexpr int WGN = 4/WGM;
  constexpr int WM = TM/WGM, WN = TN/WGN;
  constexpr int FM = WM/16, FN = WN/16;
  __shared__ char smem[(TM+TN)*128];
  char* As = smem;
  char* Bs = smem + TM*128;
  const int tid  = threadIdx.x;
  const int row0 = blockIdx.x * TM;
  const int col0 = blockIdx.y * TN;
  const int kq = tid & 7, rl = tid >> 3;       // staging: 16B chunk kq, row rl (+p*32)
  const int w = tid >> 6, lane = tid & 63;
  const int wr = (WGM==2) ? (w>>1) : 0;
  const int wc = (WGM==2) ? (w&1)  : w;

  f32x4 acc[FM][FN] = {};
  short8 aS[APASS], bS[BPASS];

  auto loadA = [&](int k0) {
    #pragma unroll
    for (int p = 0; p < APASS; ++p) {
      int r = row0 + rl + p*32;
      const char* ap;
      if (AMODE == 0) {
        if (ADT == 0) ap = (const char*)((const float*)Asrc + (size_t)r*K + k0 + kq*8);
        else          ap = (const char*)((const __hip_bfloat16*)Asrc + (size_t)r*K + k0 + kq*8);
      } else if (AMODE == 1) {
        int b = r >> 8, mm = r & 255;
        int my = mm >> 4, mx = mm & 15;
        int ch = k0 >> 8, ky = ch >> 2, kx = ch & 3;
        int tok = (4*my + ky)*64 + 4*mx + kx;
        ap = (const char*)((const float*)Asrc + ((size_t)(b*4096 + tok))*256 + (k0 & 255) + kq*8);
      } else {
        int b = r >> 10, mm = r & 1023;
        int my = mm >> 5, mx = mm & 31;
        int ch = k0 >> 8, ky = ch >> 1, kx = ch & 1;
        int tok = (2*my + ky)*64 + 2*mx + kx;
        ap = (const char*)((const float*)Asrc + ((size_t)(b*4096 + tok))*256 + (k0 & 255) + kq*8);
      }
      if (ADT == 0) {
        float4 v0 = *(const float4*)ap;
        float4 v1 = *(const float4*)(ap + 16);
        short8 s;
        s[0] = (short)bfr(v0.x); s[1] = (short)bfr(v0.y);
        s[2] = (short)bfr(v0.z); s[3] = (short)bfr(v0.w);
        s[4] = (short)bfr(v1.x); s[5] = (short)bfr(v1.y);
        s[6] = (short)bfr(v1.z); s[7] = (short)bfr(v1.w);
        aS[p] = s;
      } else {
        aS[p] = *(const short8*)ap;
      }
    }
  };
  auto loadB = [&](int k0) {
    #pragma unroll
    for (int p = 0; p < BPASS; ++p) {
      int n = col0 + rl + p*32;
      bS[p] = *(const short8*)(Bp + (size_t)n*ldb + k0 + kq*8);
    }
  };

  loadA(0); loadB(0);
  for (int k0 = 0; k0 < K; k0 += 64) {
    // stage regs -> LDS (XOR-swizzled rows of 128B)
    #pragma unroll
    for (int p = 0; p < APASS; ++p) {
      int r = rl + p*32;
      *(short8*)(As + r*128 + ((kq*16) ^ ((r&7)<<4))) = aS[p];
    }
    #pragma unroll
    for (int p = 0; p < BPASS; ++p) {
      int n = rl + p*32;
      *(short8*)(Bs + n*128 + ((kq*16) ^ ((n&7)<<4))) = bS[p];
    }
    __syncthreads();
    if (k0 + 64 < K) { loadA(k0 + 64); loadB(k0 + 64); }   // prefetch overlaps MFMA
    #pragma unroll
    for (int ks = 0; ks < 2; ++ks) {
      short8 af[FM], bfv[FN];
      #pragma unroll
      for (int i = 0; i < FM; ++i) {
        int r = wr*WM + i*16 + (lane & 15);
        af[i] = *(const short8*)(As + r*128 + ((ks*64 + (lane>>4)*16) ^ ((r&7)<<4)));
      }
      #pragma unroll
      for (int j = 0; j < FN; ++j) {
        int n = wc*WN + j*16 + (lane & 15);
        bfv[j] = *(const short8*)(Bs + n*128 + ((ks*64 + (lane>>4)*16) ^ ((n&7)<<4)));
      }
      #pragma unroll
      for (int i = 0; i < FM; ++i)
        #pragma unroll
        for (int j = 0; j < FN; ++j)
          acc[i][j] = __builtin_amdgcn_mfma_f32_16x16x32_bf16(af[i], bfv[j], acc[i][j], 0, 0, 0);
    }
    __syncthreads();
  }

  #pragma unroll
  for (int i = 0; i < FM; ++i) {
    #pragma unroll
    for (int j = 0; j < FN; ++j) {
      int cc = col0 + wc*WN + j*16 + (lane & 15);
      float bval = (EPI != 2) ? bias[cc] : 0.f;
      #pragma unroll
      for (int rg = 0; rg < 4; ++rg) {
        int rr = row0 + wr*WM + i*16 + (lane>>4)*4 + rg;
        float v = acc[i][j][rg] + bval;
        if (EPI == 0) {
          Cout[(size_t)rr*N + cc] = v;
        } else if (EPI == 1) {
          int b = rr >> 12, n = rr & 4095;
          int h = cc >> 5, d = cc & 31;
          Cout[((size_t)(b*4096 + h*512 + (n >> 3)))*256 + (n & 7)*32 + d] = v;
        } else {
          Cout[(size_t)rr*N + cc] += v;
        }
      }
    }
  }
}

// ---------------- row-wise focused-linear-attention nonlinearity (f32) ----------------
__global__ __launch_bounds__(256) void row_powernorm(float* __restrict__ x,
    const float* __restrict__ inv_sp, int rows)
{
  int row = blockIdx.x*4 + (threadIdx.x >> 6);
  if (row >= rows) return;
  int lane = threadIdx.x & 63;
  float* p = x + (size_t)row*256 + lane*4;
  float4 v = *(float4*)p;
  const float4 is = *(const float4*)(inv_sp + lane*4);
  float r0 = (fmaxf(v.x,0.f)+1e-6f)*is.x;
  float r1 = (fmaxf(v.y,0.f)+1e-6f)*is.y;
  float r2 = (fmaxf(v.z,0.f)+1e-6f)*is.z;
  float r3 = (fmaxf(v.w,0.f)+1e-6f)*is.w;
  float s2 = r0*r0+r1*r1+r2*r2+r3*r3;
  #pragma unroll
  for (int o = 1; o < 64; o <<= 1) s2 += __shfl_xor(s2, o, 64);
  float c0 = r0*r0*r0, c1 = r1*r1*r1, c2 = r2*r2*r2, c3 = r3*r3*r3;
  float s6 = c0*c0+c1*c1+c2*c2+c3*c3;
  #pragma unroll
  for (int o = 1; o < 64; o <<= 1) s6 += __shfl_xor(s6, o, 64);
  float f = sqrtf(s2/s6);
  v.x = c0*f; v.y = c1*f; v.z = c2*f; v.w = c3*f;
  *(float4*)p = v;
}

// ---------------- LayerNorm + exact GELU: f32 in, bf16 out ----------------
__global__ __launch_bounds__(256) void ln_gelu_b(const float* __restrict__ x,
    const float* __restrict__ g, const float* __restrict__ bb,
    __hip_bfloat16* __restrict__ outb, int rows)
{
  int row = blockIdx.x*4 + (threadIdx.x >> 6);
  if (row >= rows) return;
  int lane = threadIdx.x & 63;
  const float* p = x + (size_t)row*256 + lane*4;
  float4 v = *(const float4*)p;
  float s = v.x+v.y+v.z+v.w;
  #pragma unroll
  for (int o = 1; o < 64; o <<= 1) s += __shfl_xor(s, o, 64);
  float mu = s*(1.f/256.f);
  float d0 = v.x-mu, d1 = v.y-mu, d2 = v.z-mu, d3 = v.w-mu;
  float q = d0*d0+d1*d1+d2*d2+d3*d3;
  #pragma unroll
  for (int o = 1; o < 64; o <<= 1) q += __shfl_xor(q, o, 64);
  float rstd = rsqrtf(q*(1.f/256.f) + 1e-5f);
  float4 gv = *(const float4*)(g + lane*4);
  float4 bv = *(const float4*)(bb + lane*4);
  float y0 = d0*rstd*gv.x + bv.x;
  float y1 = d1*rstd*gv.y + bv.y;
  float y2 = d2*rstd*gv.z + bv.z;
  float y3 = d3*rstd*gv.w + bv.w;
  const float k = 0.70710678118654752f;
  ushort4 u;
  u.x = bfr(0.5f*y0*(1.f+erff(y0*k)));
  u.y = bfr(0.5f*y1*(1.f+erff(y1*k)));
  u.z = bfr(0.5f*y2*(1.f+erff(y2*k)));
  u.w = bfr(0.5f*y3*(1.f+erff(y3*k)));
  *(ushort4*)(outb + (size_t)row*256 + lane*4) = u;
}

// ---------------- k/v gather (transpose-scramble of y_raw) via LDS tile (f32) ----------------
template<int BR, int ISV>
__global__ __launch_bounds__(256) void gather_kv(const float* __restrict__ y,
    const float* __restrict__ pe, float* __restrict__ out)
{
  constexpr int NKV = (BR == 1) ? 256 : 1024;
  __shared__ float tile[64][65];
  int bid = blockIdx.x;
  int cb = bid & 3;
  int nb = (bid >> 2) % (NKV/64);
  int b  = (bid >> 2) / (NKV/64);
  int n0 = nb*64, c0 = cb*64;
  int tid = threadIdx.x;
  #pragma unroll
  for (int pass = 0; pass < 16; ++pass) {
    int c_l = (tid >> 6)*16 + pass;
    int c = c0 + c_l;
    int n_l;
    size_t addr;
    if (BR == 1) {
      n_l = tid & 63;
      addr = ((size_t)(b*256 + c))*512 + 2*(n0 + n_l) + ISV;
    } else {
      int u = tid & 31, pp = (tid >> 5) & 1;
      n_l = 2*u + pp;
      addr = ((size_t)(b*1024 + pp*512 + ISV*256 + c))*512 + (size_t)((n0 >> 1) + u);
    }
    tile[c_l][n_l] = y[addr];
  }
  __syncthreads();
  #pragma unroll
  for (int pass = 0; pass < 16; ++pass) {
    int n_l = (tid >> 6)*16 + pass;
    int c_l = tid & 63;
    int n = n0 + n_l, c = c0 + c_l;
    float v = tile[c_l][n_l];
    if (ISV == 0) v += pe[n*256 + c];
    out[((size_t)(b*NKV + n))*256 + c] = v;
  }
}

// ---------------- per (b,h): km = mean_n k ; kv = (1/4096) K^T V (f32) ----------------
__global__ __launch_bounds__(256) void kmkv(const float* __restrict__ kp,
    const float* __restrict__ vg, float* __restrict__ km, float* __restrict__ kvm, int nkv)
{
  int b = blockIdx.x >> 3, h = blockIdx.x & 7;
  int tid = threadIdx.x;
  __shared__ float ks[64][32];
  __shared__ float vs[64][32];
  int d  = tid >> 3;
  int e0 = (tid & 7)*4;
  float acc[4] = {0.f,0.f,0.f,0.f};
  float kmacc = 0.f;
  for (int n0 = 0; n0 < nkv; n0 += 64) {
    #pragma unroll
    for (int i = 0; i < 2; ++i) {
      int f = tid + i*256;
      int nn = f >> 3, q4 = (f & 7)*4;
      size_t base = ((size_t)(b*nkv + n0 + nn))*256 + h*32 + q4;
      *(float4*)&ks[nn][q4] = *(const float4*)(kp + base);
      *(float4*)&vs[nn][q4] = *(const float4*)(vg + base);
    }
    __syncthreads();
    #pragma unroll 8
    for (int nn = 0; nn < 64; ++nn) {
      float kd = ks[nn][d];
      kmacc += kd;
      #pragma unroll
      for (int j = 0; j < 4; ++j) acc[j] += kd * vs[nn][e0+j];
    }
    __syncthreads();
  }
  const float s2 = 1.0f/4096.0f;
  #pragma unroll
  for (int j = 0; j < 4; ++j)
    kvm[(((size_t)(b*8 + h))*32 + d)*32 + e0 + j] = acc[j]*s2;
  if ((tid & 7) == 0) km[(b*8 + h)*32 + d] = kmacc / (float)nkv;
}

// ---------------- single-branch attention matvec -> A (bf16) ----------------
__global__ __launch_bounds__(256) void attn_single(const float* __restrict__ q,
    const float* __restrict__ km, const float* __restrict__ kv, __hip_bfloat16* __restrict__ A)
{
  __shared__ float kvs[8*1057];
  __shared__ float kms[8*33];
  int b  = blockIdx.x >> 7;
  int t0 = (blockIdx.x & 127)*32;
  int tid = threadIdx.x;
  int h = tid & 7, tl = tid >> 3;
  int t = t0 + tl;
  for (int i = tid; i < 8*1024; i += 256) {
    int hh = i >> 10, de = i & 1023;
    kvs[hh*1057 + (de >> 5)*33 + (de & 31)] = kv[((size_t)(b*8 + hh))*1024 + de];
  }
  kms[(tid >> 5)*33 + (tid & 31)] = km[(size_t)b*256 + tid];
  float qreg[32];
  #pragma unroll
  for (int j = 0; j < 8; ++j) {
    float4 v = *(const float4*)(q + ((size_t)(b*4096 + t))*256 + h*32 + j*4);
    qreg[4*j+0] = v.x; qreg[4*j+1] = v.y; qreg[4*j+2] = v.z; qreg[4*j+3] = v.w;
  }
  __syncthreads();
  float dot = 0.f;
  #pragma unroll
  for (int d = 0; d < 32; ++d) dot += qreg[d]*kms[h*33 + d];
  float z = 1.0f/(dot + 1e-6f);
  float acc[32] = {};
  const float* kvp = &kvs[h*1057];
  #pragma unroll
  for (int d = 0; d < 32; ++d) {
    float qd = qreg[d];
    #pragma unroll
    for (int e = 0; e < 32; ++e) acc[e] += qd * kvp[d*33 + e];
  }
  __hip_bfloat16* outp = A + ((size_t)(b*4096 + t))*256 + h*32;
  #pragma unroll
  for (int j = 0; j < 8; ++j) {
    ushort4 u;
    u.x = bfr(acc[4*j+0]*z); u.y = bfr(acc[4*j+1]*z);
    u.z = bfr(acc[4*j+2]*z); u.w = bfr(acc[4*j+3]*z);
    *(ushort4*)(outp + 4*j) = u;
  }
}

// ---------------- fused interp + 5x5 depthwise conv (pad 2), RMW on bf16 A ----------------
template<int BR>
__global__ __launch_bounds__(256) void dwconv_fused(const float* __restrict__ vg,
    const float* __restrict__ Wd, const float* __restrict__ bias, __hip_bfloat16* __restrict__ A)
{
  constexpr int L    = (BR == 1) ? 256 : 1024;
  constexpr int RPSH = (BR == 1) ? 5 : 7;
  int bid = blockIdx.x;            // (b*8 + e)*64 + y
  int y = bid & 63; bid >>= 6;
  int e = bid & 7;
  int b = bid >> 3;
  int tid = threadIdx.x;
  int d = tid & 31, xg = tid >> 5;
  float w[25];
  #pragma unroll
  for (int i = 0; i < 25; ++i) w[i] = Wd[d*25 + i];
  float acc[8] = {};
  #pragma unroll
  for (int dy = 0; dy < 5; ++dy) {
    int yy = y + dy - 2;
    if (yy >= 0 && yy <= 63) {
      float in[12];
      #pragma unroll
      for (int i = 0; i < 12; ++i) {
        int xx = xg*8 - 2 + i;
        if (xx < 0 || xx > 63) { in[i] = 0.f; }
        else {
          int t = e*512 + yy*8 + (xx >> 3);
          float cpos = ((float)t + 0.5f) * ((float)L / 4096.0f) - 0.5f;
          cpos = fminf(fmaxf(cpos, 0.0f), (float)(L-1));
          int i0 = (int)cpos;
          float wt = cpos - (float)i0;
          int i1 = (i0 + 1 < L) ? i0 + 1 : L - 1;
          int xl = xx & 7;
          int n0 = ((i0 & ((L/8)-1)) << 3) + xl, ch0 = ((i0 >> RPSH) << 5) + d;
          int n1 = ((i1 & ((L/8)-1)) << 3) + xl, ch1 = ((i1 >> RPSH) << 5) + d;
          float v0 = vg[((size_t)(b*L + n0))*256 + ch0];
          float v1 = vg[((size_t)(b*L + n1))*256 + ch1];
          in[i] = v0 + (v1 - v0)*wt;
        }
      }
      #pragma unroll
      for (int dx = 0; dx < 5; ++dx) {
        float ww = w[dy*5 + dx];
        #pragma unroll
        for (int j = 0; j < 8; ++j) acc[j] += ww * in[j + dx];
      }
    }
  }
  float bv = bias[d];
  #pragma unroll
  for (int j = 0; j < 8; ++j) {
    size_t o = ((size_t)(b*4096 + y*64 + xg*8 + j))*256 + e*32 + d;
    float cur = __bfloat162float(A[o]);
    A[o] = __float2bfloat16(cur + acc[j] + bv);
  }
}

// ---------------- launcher ----------------
extern "C" void kernel_launch(void* const* d_in, const int* in_sizes, int n_in,
                              void* d_out, int out_size, void* d_ws, size_t ws_size,
                              hipStream_t stream)
{
  (void)in_sizes; (void)n_in; (void)out_size; (void)ws_size;
  const float* x     = (const float*)d_in[0];
  const float* Wq    = (const float*)d_in[1];
  const float* bq    = (const float*)d_in[2];
  const float* Wsr1  = (const float*)d_in[3];
  const float* bsr1  = (const float*)d_in[4];
  const float* g1    = (const float*)d_in[5];
  const float* b1    = (const float*)d_in[6];
  const float* Wsr2  = (const float*)d_in[7];
  const float* bsr2  = (const float*)d_in[8];
  const float* g2    = (const float*)d_in[9];
  const float* b2    = (const float*)d_in[10];
  const float* Wkv1  = (const float*)d_in[11];
  const float* bkv1  = (const float*)d_in[12];
  const float* Wkv2  = (const float*)d_in[13];
  const float* bkv2  = (const float*)d_in[14];
  const float* pe1   = (const float*)d_in[15];
  const float* pe2   = (const float*)d_in[16];
  const float* Wproj = (const float*)d_in[17];
  const float* bproj = (const float*)d_in[18];
  const float* Wdwc  = (const float*)d_in[19];
  const float* bdwc  = (const float*)d_in[20];
  const float* scale = (const float*)d_in[21];
  float* out = (float*)d_out;
  float* ws  = (float*)d_ws;
  dim3 blk(256);

  __hip_bfloat16* WQB    = (__hip_bfloat16*)(ws + oWQB);
  __hip_bfloat16* W1B    = (__hip_bfloat16*)(ws + oW1B);
  __hip_bfloat16* W2B    = (__hip_bfloat16*)(ws + oW2B);
  __hip_bfloat16* WKV1B  = (__hip_bfloat16*)(ws + oWKV1B);
  __hip_bfloat16* WKV2B  = (__hip_bfloat16*)(ws + oWKV2B);
  __hip_bfloat16* WPROJB = (__hip_bfloat16*)(ws + oWPROJB);
  __hip_bfloat16* X1B    = (__hip_bfloat16*)(ws + oX1B);
  __hip_bfloat16* X2B    = (__hip_bfloat16*)(ws + oX2B);
  __hip_bfloat16* AB     = (__hip_bfloat16*)(ws + oAB);

  // weight packs (Wq/Wkv/Wproj are already [N][K] row-major — plain cast)
  cast_bf16_k<<<256,  blk, 0, stream>>>(Wq,    WQB,    65536);
  cast_bf16_k<<<512,  blk, 0, stream>>>(Wkv1,  WKV1B,  131072);
  cast_bf16_k<<<512,  blk, 0, stream>>>(Wkv2,  WKV2B,  131072);
  cast_bf16_k<<<512,  blk, 0, stream>>>(Wproj, WPROJB, 131072);
  pack_conv_bf16<<<4096, blk, 0, stream>>>(Wsr1, W1B, 16);
  pack_conv_bf16<<<1024, blk, 0, stream>>>(Wsr2, W2B, 4);
  softplus_inv_k<<<1, blk, 0, stream>>>(scale, ws + oINVSP);

  // q = x@Wq^T + bq (scatter epilogue), then power-norm
  gmfma<128,128,0,0,1><<<dim3(512,2), blk, 0, stream>>>(x, WQB, bq, ws+oQBUF, 65536, 256, 256, 256);
  row_powernorm<<<16384, blk, 0, stream>>>(ws+oQBUF, ws+oINVSP, 65536);

  // ---- branch 1 staging ----
  gmfma<64,64,1,0,0><<<dim3(64,4), blk, 0, stream>>>(x, W1B, bsr1, ws+oX1, 4096, 256, 4096, 4096);
  ln_gelu_b<<<1024, blk, 0, stream>>>(ws+oX1, g1, b1, X1B, 4096);
  gmfma<64,128,0,1,0><<<dim3(64,4), blk, 0, stream>>>(X1B, WKV1B, bkv1, ws+oY1, 4096, 512, 256, 256);
  gather_kv<1,0><<<256, blk, 0, stream>>>(ws+oY1, pe1, ws+oK1P);
  gather_kv<1,1><<<256, blk, 0, stream>>>(ws+oY1, pe1, ws+oV1G);
  row_powernorm<<<1024, blk, 0, stream>>>(ws+oK1P, ws+oINVSP, 4096);
  kmkv<<<128, blk, 0, stream>>>(ws+oK1P, ws+oV1G, ws+oKM1, ws+oKV1M, 256);

  // ---- branch 2 staging ----
  gmfma<128,128,2,0,0><<<dim3(128,2), blk, 0, stream>>>(x, W2B, bsr2, ws+oX2, 16384, 256, 1024, 1024);
  ln_gelu_b<<<4096, blk, 0, stream>>>(ws+oX2, g2, b2, X2B, 16384);
  gmfma<128,128,0,1,0><<<dim3(128,4), blk, 0, stream>>>(X2B, WKV2B, bkv2, ws+oY2, 16384, 512, 256, 256);
  gather_kv<2,0><<<1024, blk, 0, stream>>>(ws+oY2, pe2, ws+oK2P);
  gather_kv<2,1><<<1024, blk, 0, stream>>>(ws+oY2, pe2, ws+oV2G);
  row_powernorm<<<4096, blk, 0, stream>>>(ws+oK2P, ws+oINVSP, 16384);
  kmkv<<<128, blk, 0, stream>>>(ws+oK2P, ws+oV2G, ws+oKM2, ws+oKV2M, 1024);

  // ---- branch 1 output path ----
  attn_single<<<cB*128, blk, 0, stream>>>(ws+oQBUF, ws+oKM1, ws+oKV1M, AB);
  dwconv_fused<1><<<cB*8*64, blk, 0, stream>>>(ws+oV1G, Wdwc, bdwc, AB);
  gmfma<128,128,0,1,0><<<dim3(512,2), blk, 0, stream>>>(AB, WPROJB, bproj, out, 65536, 256, 256, 512);

  // ---- branch 2 output path ----
  attn_single<<<cB*128, blk, 0, stream>>>(ws+oQBUF, ws+oKM2, ws+oKV2M, AB);
  dwconv_fused<2><<<cB*8*64, blk, 0, stream>>>(ws+oV2G, Wdwc, bdwc, AB);
  gmfma<128,128,0,1,2><<<dim3(512,2), blk, 0, stream>>>(AB, WPROJB + 256, bproj, out, 65536, 256, 256, 512);
}

// Round 4
// 515.400 us; speedup vs baseline: 2.4288x; 1.3195x over previous
//
#include <hip/hip_runtime.h>
#include <hip/hip_bf16.h>
#include <cmath>

// ---------------- problem constants ----------------
constexpr int cB = 16;
constexpr int cN = 4096;
constexpr int cC = 256;

typedef __attribute__((ext_vector_type(8))) short short8;
typedef __attribute__((ext_vector_type(4))) float f32x4;

__device__ inline unsigned short bfr(float f) {
  __hip_bfloat16 h = __float2bfloat16(f);
  return *(unsigned short*)&h;
}

// ---------------- workspace layout (float units) — total 39,953,408 floats = 159.8 MB ----------------
constexpr size_t oWQB    = 0;                               // 256x256 bf16
constexpr size_t oW1B    = oWQB    + 32768;                 // 256x4096 bf16
constexpr size_t oW2B    = oW1B    + 524288;                // 256x1024 bf16
constexpr size_t oWKV1B  = oW2B    + 131072;                // 512x256 bf16
constexpr size_t oWKV2B  = oWKV1B  + 65536;                 // 512x256 bf16
constexpr size_t oWPROJB = oWKV2B  + 65536;                 // 256x512 bf16
constexpr size_t oINVSP  = oWPROJB + 65536;                 // 256 f32 (pad 1024)
constexpr size_t oKM1    = oINVSP  + 1024;
constexpr size_t oKV1M   = oKM1    + 4096;
constexpr size_t oKM2    = oKV1M   + 131072;
constexpr size_t oKV2M   = oKM2    + 4096;
constexpr size_t oQBUF   = oKV2M   + 131072;                // B*N*C f32 q (scattered); later = interp image
constexpr size_t oV1G    = oQBUF   + 16777216;              // B*256*256 f32
constexpr size_t oV2G    = oV1G    + 1048576;               // B*1024*256 f32
constexpr size_t oU      = oV2G    + 4194304;               // union region, 16,777,216 f32
// phase 1 (branch-1 staging):
constexpr size_t oX1     = oU;                              // B*256*256 f32
constexpr size_t oY1     = oU  + 1048576;                   // B*256*512 f32
constexpr size_t oX1B    = oU  + 3145728;                   // bf16
constexpr size_t oK1P    = oU;                              // aliases X1 (dead)
// phase 2 (branch-2 staging):
constexpr size_t oX2     = oU;                              // B*1024*256 f32
constexpr size_t oY2     = oU  + 4194304;                   // B*1024*512 f32
constexpr size_t oX2B    = oU  + 12582912;                  // bf16
constexpr size_t oK2P    = oU;                              // aliases X2 (dead)
// phase 3: AB = B*N*512 bf16 (16,777,216 f32 units)
constexpr size_t oAB     = oU;

// ---------------- weight packs ----------------
__global__ void cast_bf16_k(const float* __restrict__ src, __hip_bfloat16* __restrict__ dst, int n) {
  int idx = blockIdx.x*256 + threadIdx.x;
  if (idx < n) dst[idx] = __float2bfloat16(src[idx]);
}

__global__ void pack_conv_bf16(const float* __restrict__ src, __hip_bfloat16* __restrict__ dst, int KHW) {
  int idx = blockIdx.x*256 + threadIdx.x;   // ((co*KHW+p)*256+ci)
  if (idx >= 65536*KHW) return;
  int ci = idx & 255;
  int rest = idx >> 8;
  int p = rest % KHW, co = rest / KHW;
  dst[idx] = __float2bfloat16(src[((size_t)co*256 + ci)*KHW + p]);
}

__global__ void softplus_inv_k(const float* __restrict__ s, float* __restrict__ inv) {
  int c = threadIdx.x;
  float v = s[c];
  float sp = (v > 20.f) ? v : log1pf(expf(v));
  inv[c] = 1.f/sp;
}

// ---------------- MFMA bf16 GEMM ----------------
template<int TM, int TN, int AMODE, int ADT, int EPI>
__global__ __launch_bounds__(256) void gmfma(
    const void* __restrict__ Asrc, const __hip_bfloat16* __restrict__ Bp,
    const float* __restrict__ bias, float* __restrict__ Cout,
    int M, int N, int K, int ldb)
{
  constexpr int APASS = TM/32, BPASS = TN/32;
  constexpr int WGM = (TM==128) ? 2 : ((TN==64) ? 2 : 1);
  constexpr int WGN = 4/WGM;
  constexpr int WM = TM/WGM, WN = TN/WGN;
  constexpr int FM = WM/16, FN = WN/16;
  __shared__ char smem[(TM+TN)*128];
  char* As = smem;
  char* Bs = smem + TM*128;
  const int tid  = threadIdx.x;
  const int row0 = blockIdx.x * TM;
  const int col0 = blockIdx.y * TN;
  const int kq = tid & 7, rl = tid >> 3;
  const int w = tid >> 6, lane = tid & 63;
  const int wr = (WGM==2) ? (w>>1) : 0;
  const int wc = (WGM==2) ? (w&1)  : w;

  f32x4 acc[FM][FN] = {};
  short8 aS[APASS], bS[BPASS];

  auto loadA = [&](int k0) {
    #pragma unroll
    for (int p = 0; p < APASS; ++p) {
      int r = row0 + rl + p*32;
      const char* ap;
      if (AMODE == 0) {
        if (ADT == 0) ap = (const char*)((const float*)Asrc + (size_t)r*K + k0 + kq*8);
        else          ap = (const char*)((const __hip_bfloat16*)Asrc + (size_t)r*K + k0 + kq*8);
      } else if (AMODE == 1) {
        int b = r >> 8, mm = r & 255;
        int my = mm >> 4, mx = mm & 15;
        int ch = k0 >> 8, ky = ch >> 2, kx = ch & 3;
        int tok = (4*my + ky)*64 + 4*mx + kx;
        ap = (const char*)((const float*)Asrc + ((size_t)(b*4096 + tok))*256 + (k0 & 255) + kq*8);
      } else {
        int b = r >> 10, mm = r & 1023;
        int my = mm >> 5, mx = mm & 31;
        int ch = k0 >> 8, ky = ch >> 1, kx = ch & 1;
        int tok = (2*my + ky)*64 + 2*mx + kx;
        ap = (const char*)((const float*)Asrc + ((size_t)(b*4096 + tok))*256 + (k0 & 255) + kq*8);
      }
      if (ADT == 0) {
        float4 v0 = *(const float4*)ap;
        float4 v1 = *(const float4*)(ap + 16);
        short8 s;
        s[0] = (short)bfr(v0.x); s[1] = (short)bfr(v0.y);
        s[2] = (short)bfr(v0.z); s[3] = (short)bfr(v0.w);
        s[4] = (short)bfr(v1.x); s[5] = (short)bfr(v1.y);
        s[6] = (short)bfr(v1.z); s[7] = (short)bfr(v1.w);
        aS[p] = s;
      } else {
        aS[p] = *(const short8*)ap;
      }
    }
  };
  auto loadB = [&](int k0) {
    #pragma unroll
    for (int p = 0; p < BPASS; ++p) {
      int n = col0 + rl + p*32;
      bS[p] = *(const short8*)(Bp + (size_t)n*ldb + k0 + kq*8);
    }
  };

  loadA(0); loadB(0);
  for (int k0 = 0; k0 < K; k0 += 64) {
    #pragma unroll
    for (int p = 0; p < APASS; ++p) {
      int r = rl + p*32;
      *(short8*)(As + r*128 + ((kq*16) ^ ((r&7)<<4))) = aS[p];
    }
    #pragma unroll
    for (int p = 0; p < BPASS; ++p) {
      int n = rl + p*32;
      *(short8*)(Bs + n*128 + ((kq*16) ^ ((n&7)<<4))) = bS[p];
    }
    __syncthreads();
    if (k0 + 64 < K) { loadA(k0 + 64); loadB(k0 + 64); }
    #pragma unroll
    for (int ks = 0; ks < 2; ++ks) {
      short8 af[FM], bfv[FN];
      #pragma unroll
      for (int i = 0; i < FM; ++i) {
        int r = wr*WM + i*16 + (lane & 15);
        af[i] = *(const short8*)(As + r*128 + ((ks*64 + (lane>>4)*16) ^ ((r&7)<<4)));
      }
      #pragma unroll
      for (int j = 0; j < FN; ++j) {
        int n = wc*WN + j*16 + (lane & 15);
        bfv[j] = *(const short8*)(Bs + n*128 + ((ks*64 + (lane>>4)*16) ^ ((n&7)<<4)));
      }
      #pragma unroll
      for (int i = 0; i < FM; ++i)
        #pragma unroll
        for (int j = 0; j < FN; ++j)
          acc[i][j] = __builtin_amdgcn_mfma_f32_16x16x32_bf16(af[i], bfv[j], acc[i][j], 0, 0, 0);
    }
    __syncthreads();
  }

  #pragma unroll
  for (int i = 0; i < FM; ++i) {
    #pragma unroll
    for (int j = 0; j < FN; ++j) {
      int cc = col0 + wc*WN + j*16 + (lane & 15);
      float bval = bias[cc];
      #pragma unroll
      for (int rg = 0; rg < 4; ++rg) {
        int rr = row0 + wr*WM + i*16 + (lane>>4)*4 + rg;
        float v = acc[i][j][rg] + bval;
        if (EPI == 0) {
          Cout[(size_t)rr*N + cc] = v;
        } else {
          int b = rr >> 12, n = rr & 4095;
          int h = cc >> 5, d = cc & 31;
          Cout[((size_t)(b*4096 + h*512 + (n >> 3)))*256 + (n & 7)*32 + d] = v;
        }
      }
    }
  }
}

// ---------------- row-wise focused-linear-attention nonlinearity (f32) ----------------
__global__ __launch_bounds__(256) void row_powernorm(float* __restrict__ x,
    const float* __restrict__ inv_sp, int rows)
{
  int row = blockIdx.x*4 + (threadIdx.x >> 6);
  if (row >= rows) return;
  int lane = threadIdx.x & 63;
  float* p = x + (size_t)row*256 + lane*4;
  float4 v = *(float4*)p;
  const float4 is = *(const float4*)(inv_sp + lane*4);
  float r0 = (fmaxf(v.x,0.f)+1e-6f)*is.x;
  float r1 = (fmaxf(v.y,0.f)+1e-6f)*is.y;
  float r2 = (fmaxf(v.z,0.f)+1e-6f)*is.z;
  float r3 = (fmaxf(v.w,0.f)+1e-6f)*is.w;
  float s2 = r0*r0+r1*r1+r2*r2+r3*r3;
  #pragma unroll
  for (int o = 1; o < 64; o <<= 1) s2 += __shfl_xor(s2, o, 64);
  float c0 = r0*r0*r0, c1 = r1*r1*r1, c2 = r2*r2*r2, c3 = r3*r3*r3;
  float s6 = c0*c0+c1*c1+c2*c2+c3*c3;
  #pragma unroll
  for (int o = 1; o < 64; o <<= 1) s6 += __shfl_xor(s6, o, 64);
  float f = sqrtf(s2/s6);
  v.x = c0*f; v.y = c1*f; v.z = c2*f; v.w = c3*f;
  *(float4*)p = v;
}

// ---------------- LayerNorm + exact GELU: f32 in, bf16 out ----------------
__global__ __launch_bounds__(256) void ln_gelu_b(const float* __restrict__ x,
    const float* __restrict__ g, const float* __restrict__ bb,
    __hip_bfloat16* __restrict__ outb, int rows)
{
  int row = blockIdx.x*4 + (threadIdx.x >> 6);
  if (row >= rows) return;
  int lane = threadIdx.x & 63;
  const float* p = x + (size_t)row*256 + lane*4;
  float4 v = *(const float4*)p;
  float s = v.x+v.y+v.z+v.w;
  #pragma unroll
  for (int o = 1; o < 64; o <<= 1) s += __shfl_xor(s, o, 64);
  float mu = s*(1.f/256.f);
  float d0 = v.x-mu, d1 = v.y-mu, d2 = v.z-mu, d3 = v.w-mu;
  float q = d0*d0+d1*d1+d2*d2+d3*d3;
  #pragma unroll
  for (int o = 1; o < 64; o <<= 1) q += __shfl_xor(q, o, 64);
  float rstd = rsqrtf(q*(1.f/256.f) + 1e-5f);
  float4 gv = *(const float4*)(g + lane*4);
  float4 bv = *(const float4*)(bb + lane*4);
  float y0 = d0*rstd*gv.x + bv.x;
  float y1 = d1*rstd*gv.y + bv.y;
  float y2 = d2*rstd*gv.z + bv.z;
  float y3 = d3*rstd*gv.w + bv.w;
  const float k = 0.70710678118654752f;
  ushort4 u;
  u.x = bfr(0.5f*y0*(1.f+erff(y0*k)));
  u.y = bfr(0.5f*y1*(1.f+erff(y1*k)));
  u.z = bfr(0.5f*y2*(1.f+erff(y2*k)));
  u.w = bfr(0.5f*y3*(1.f+erff(y3*k)));
  *(ushort4*)(outb + (size_t)row*256 + lane*4) = u;
}

// ---------------- k/v gather via LDS tile (f32) ----------------
template<int BR, int ISV>
__global__ __launch_bounds__(256) void gather_kv(const float* __restrict__ y,
    const float* __restrict__ pe, float* __restrict__ out)
{
  constexpr int NKV = (BR == 1) ? 256 : 1024;
  __shared__ float tile[64][65];
  int bid = blockIdx.x;
  int cb = bid & 3;
  int nb = (bid >> 2) % (NKV/64);
  int b  = (bid >> 2) / (NKV/64);
  int n0 = nb*64, c0 = cb*64;
  int tid = threadIdx.x;
  #pragma unroll
  for (int pass = 0; pass < 16; ++pass) {
    int c_l = (tid >> 6)*16 + pass;
    int c = c0 + c_l;
    int n_l;
    size_t addr;
    if (BR == 1) {
      n_l = tid & 63;
      addr = ((size_t)(b*256 + c))*512 + 2*(n0 + n_l) + ISV;
    } else {
      int u = tid & 31, pp = (tid >> 5) & 1;
      n_l = 2*u + pp;
      addr = ((size_t)(b*1024 + pp*512 + ISV*256 + c))*512 + (size_t)((n0 >> 1) + u);
    }
    tile[c_l][n_l] = y[addr];
  }
  __syncthreads();
  #pragma unroll
  for (int pass = 0; pass < 16; ++pass) {
    int n_l = (tid >> 6)*16 + pass;
    int c_l = tid & 63;
    int n = n0 + n_l, c = c0 + c_l;
    float v = tile[c_l][n_l];
    if (ISV == 0) v += pe[n*256 + c];
    out[((size_t)(b*NKV + n))*256 + c] = v;
  }
}

// ---------------- per (b,h): km = mean_n k ; kv = (1/4096) K^T V (f32) ----------------
__global__ __launch_bounds__(256) void kmkv(const float* __restrict__ kp,
    const float* __restrict__ vg, float* __restrict__ km, float* __restrict__ kvm, int nkv)
{
  int b = blockIdx.x >> 3, h = blockIdx.x & 7;
  int tid = threadIdx.x;
  __shared__ float ks[64][32];
  __shared__ float vs[64][32];
  int d  = tid >> 3;
  int e0 = (tid & 7)*4;
  float acc[4] = {0.f,0.f,0.f,0.f};
  float kmacc = 0.f;
  for (int n0 = 0; n0 < nkv; n0 += 64) {
    #pragma unroll
    for (int i = 0; i < 2; ++i) {
      int f = tid + i*256;
      int nn = f >> 3, q4 = (f & 7)*4;
      size_t base = ((size_t)(b*nkv + n0 + nn))*256 + h*32 + q4;
      *(float4*)&ks[nn][q4] = *(const float4*)(kp + base);
      *(float4*)&vs[nn][q4] = *(const float4*)(vg + base);
    }
    __syncthreads();
    #pragma unroll 8
    for (int nn = 0; nn < 64; ++nn) {
      float kd = ks[nn][d];
      kmacc += kd;
      #pragma unroll
      for (int j = 0; j < 4; ++j) acc[j] += kd * vs[nn][e0+j];
    }
    __syncthreads();
  }
  const float s2 = 1.0f/4096.0f;
  #pragma unroll
  for (int j = 0; j < 4; ++j)
    kvm[(((size_t)(b*8 + h))*32 + d)*32 + e0 + j] = acc[j]*s2;
  if ((tid & 7) == 0) km[(b*8 + h)*32 + d] = kmacc / (float)nkv;
}

// ---------------- single-branch attention matvec -> AB (bf16, row stride 512) ----------------
__global__ __launch_bounds__(256) void attn_single(const float* __restrict__ q,
    const float* __restrict__ km, const float* __restrict__ kv,
    __hip_bfloat16* __restrict__ A, int broff)
{
  __shared__ float kvs[8*1057];
  __shared__ float kms[8*33];
  int b  = blockIdx.x >> 7;
  int t0 = (blockIdx.x & 127)*32;
  int tid = threadIdx.x;
  int h = tid & 7, tl = tid >> 3;
  int t = t0 + tl;
  for (int i = tid; i < 8*1024; i += 256) {
    int hh = i >> 10, de = i & 1023;
    kvs[hh*1057 + (de >> 5)*33 + (de & 31)] = kv[((size_t)(b*8 + hh))*1024 + de];
  }
  kms[(tid >> 5)*33 + (tid & 31)] = km[(size_t)b*256 + tid];
  float qreg[32];
  #pragma unroll
  for (int j = 0; j < 8; ++j) {
    float4 v = *(const float4*)(q + ((size_t)(b*4096 + t))*256 + h*32 + j*4);
    qreg[4*j+0] = v.x; qreg[4*j+1] = v.y; qreg[4*j+2] = v.z; qreg[4*j+3] = v.w;
  }
  __syncthreads();
  float dot = 0.f;
  #pragma unroll
  for (int d = 0; d < 32; ++d) dot += qreg[d]*kms[h*33 + d];
  float z = 1.0f/(dot + 1e-6f);
  float acc[32] = {};
  const float* kvp = &kvs[h*1057];
  #pragma unroll
  for (int d = 0; d < 32; ++d) {
    float qd = qreg[d];
    #pragma unroll
    for (int e = 0; e < 32; ++e) acc[e] += qd * kvp[d*33 + e];
  }
  __hip_bfloat16* outp = A + ((size_t)(b*4096 + t))*512 + broff + h*32;
  #pragma unroll
  for (int j = 0; j < 8; ++j) {
    ushort4 u;
    u.x = bfr(acc[4*j+0]*z); u.y = bfr(acc[4*j+1]*z);
    u.z = bfr(acc[4*j+2]*z); u.w = bfr(acc[4*j+3]*z);
    *(ushort4*)(outp + 4*j) = u;
  }
}

// ---------------- interp -> image-layout tmp: img[(b*8+e)*4096 + y*64 + x][d] ----------------
// v2[b,t,c]: e=t>>9, y=(t>>3)&63, x=(t&7)*8+(c>>5), d=c&31
template<int BR>
__global__ __launch_bounds__(256) void interp_img(const float* __restrict__ vg, float* __restrict__ img) {
  constexpr int L    = (BR == 1) ? 256 : 1024;
  constexpr int RPSH = (BR == 1) ? 5 : 7;   // log2(L/8)
  int row = blockIdx.x*4 + (threadIdx.x >> 6);   // b*4096 + t
  int lane = threadIdx.x & 63;
  int b = row >> 12, t = row & 4095;
  float cpos = ((float)t + 0.5f) * ((float)L / 4096.0f) - 0.5f;
  cpos = fminf(fmaxf(cpos, 0.0f), (float)(L-1));
  int i0 = (int)cpos;
  float w = cpos - (float)i0;
  int i1 = (i0 + 1 < L) ? i0 + 1 : L - 1;
  int cc = lane*4;
  int n0 = ((i0 & ((L/8)-1)) << 3) + (cc >> 5), ch0 = ((i0 >> RPSH) << 5) + (cc & 31);
  int n1 = ((i1 & ((L/8)-1)) << 3) + (cc >> 5), ch1 = ((i1 >> RPSH) << 5) + (cc & 31);
  float4 v0 = *(const float4*)(vg + ((size_t)(b*L + n0))*256 + ch0);
  float4 v1 = *(const float4*)(vg + ((size_t)(b*L + n1))*256 + ch1);
  float4 o;
  o.x = v0.x + (v1.x - v0.x)*w;
  o.y = v0.y + (v1.y - v0.y)*w;
  o.z = v0.z + (v1.z - v0.z)*w;
  o.w = v0.w + (v1.w - v0.w)*w;
  size_t off = ((size_t)((b*8 + (t >> 9))*4096 + ((t >> 3) & 63)*64 + (t & 7)*8 + (cc >> 5)))*32 + (cc & 31);
  *(float4*)(img + off) = o;
}

// ---------------- 5x5 depthwise conv (pad 2) on image tmp, RMW into bf16 AB ----------------
__global__ __launch_bounds__(256) void dwconv_clean(const float* __restrict__ img,
    const float* __restrict__ Wd, const float* __restrict__ bias,
    __hip_bfloat16* __restrict__ A, int broff)
{
  int bid = blockIdx.x;            // (b*8+e)*64 + y
  int y  = bid & 63;
  int be = bid >> 6;               // b*8+e
  int tid = threadIdx.x;
  int d = tid & 31, xg = tid >> 5;
  const float* base = img + (size_t)be*131072 + d;   // 4096*32
  float w[25];
  #pragma unroll
  for (int i = 0; i < 25; ++i) w[i] = Wd[d*25 + i];
  float acc[8] = {};
  #pragma unroll
  for (int dy = 0; dy < 5; ++dy) {
    int yy = y + dy - 2;
    if (yy >= 0 && yy <= 63) {
      const float* rb = base + yy*2048;
      float in[12];
      #pragma unroll
      for (int i = 0; i < 12; ++i) {
        int xx = xg*8 - 2 + i;
        in[i] = (xx < 0 || xx > 63) ? 0.f : rb[xx*32];
      }
      #pragma unroll
      for (int dx = 0; dx < 5; ++dx) {
        float ww = w[dy*5 + dx];
        #pragma unroll
        for (int j = 0; j < 8; ++j) acc[j] += ww * in[j + dx];
      }
    }
  }
  int b = be >> 3, e = be & 7;
  float bv = bias[d];
  #pragma unroll
  for (int j = 0; j < 8; ++j) {
    size_t o = ((size_t)(b*4096 + y*64 + xg*8 + j))*512 + broff + e*32 + d;
    float cur = __bfloat162float(A[o]);
    A[o] = __float2bfloat16(cur + acc[j] + bv);
  }
}

// ---------------- launcher ----------------
extern "C" void kernel_launch(void* const* d_in, const int* in_sizes, int n_in,
                              void* d_out, int out_size, void* d_ws, size_t ws_size,
                              hipStream_t stream)
{
  (void)in_sizes; (void)n_in; (void)out_size; (void)ws_size;
  const float* x     = (const float*)d_in[0];
  const float* Wq    = (const float*)d_in[1];
  const float* bq    = (const float*)d_in[2];
  const float* Wsr1  = (const float*)d_in[3];
  const float* bsr1  = (const float*)d_in[4];
  const float* g1    = (const float*)d_in[5];
  const float* b1    = (const float*)d_in[6];
  const float* Wsr2  = (const float*)d_in[7];
  const float* bsr2  = (const float*)d_in[8];
  const float* g2    = (const float*)d_in[9];
  const float* b2    = (const float*)d_in[10];
  const float* Wkv1  = (const float*)d_in[11];
  const float* bkv1  = (const float*)d_in[12];
  const float* Wkv2  = (const float*)d_in[13];
  const float* bkv2  = (const float*)d_in[14];
  const float* pe1   = (const float*)d_in[15];
  const float* pe2   = (const float*)d_in[16];
  const float* Wproj = (const float*)d_in[17];
  const float* bproj = (const float*)d_in[18];
  const float* Wdwc  = (const float*)d_in[19];
  const float* bdwc  = (const float*)d_in[20];
  const float* scale = (const float*)d_in[21];
  float* out = (float*)d_out;
  float* ws  = (float*)d_ws;
  dim3 blk(256);

  __hip_bfloat16* WQB    = (__hip_bfloat16*)(ws + oWQB);
  __hip_bfloat16* W1B    = (__hip_bfloat16*)(ws + oW1B);
  __hip_bfloat16* W2B    = (__hip_bfloat16*)(ws + oW2B);
  __hip_bfloat16* WKV1B  = (__hip_bfloat16*)(ws + oWKV1B);
  __hip_bfloat16* WKV2B  = (__hip_bfloat16*)(ws + oWKV2B);
  __hip_bfloat16* WPROJB = (__hip_bfloat16*)(ws + oWPROJB);
  __hip_bfloat16* X1B    = (__hip_bfloat16*)(ws + oX1B);
  __hip_bfloat16* X2B    = (__hip_bfloat16*)(ws + oX2B);
  __hip_bfloat16* AB     = (__hip_bfloat16*)(ws + oAB);

  // weight packs
  cast_bf16_k<<<256,  blk, 0, stream>>>(Wq,    WQB,    65536);
  cast_bf16_k<<<512,  blk, 0, stream>>>(Wkv1,  WKV1B,  131072);
  cast_bf16_k<<<512,  blk, 0, stream>>>(Wkv2,  WKV2B,  131072);
  cast_bf16_k<<<512,  blk, 0, stream>>>(Wproj, WPROJB, 131072);
  pack_conv_bf16<<<4096, blk, 0, stream>>>(Wsr1, W1B, 16);
  pack_conv_bf16<<<1024, blk, 0, stream>>>(Wsr2, W2B, 4);
  softplus_inv_k<<<1, blk, 0, stream>>>(scale, ws + oINVSP);

  // q = x@Wq^T + bq (scatter epilogue), then power-norm
  gmfma<128,128,0,0,1><<<dim3(512,2), blk, 0, stream>>>(x, WQB, bq, ws+oQBUF, 65536, 256, 256, 256);
  row_powernorm<<<16384, blk, 0, stream>>>(ws+oQBUF, ws+oINVSP, 65536);

  // ---- branch 1 staging ----
  gmfma<64,64,1,0,0><<<dim3(64,4), blk, 0, stream>>>(x, W1B, bsr1, ws+oX1, 4096, 256, 4096, 4096);
  ln_gelu_b<<<1024, blk, 0, stream>>>(ws+oX1, g1, b1, X1B, 4096);
  gmfma<64,128,0,1,0><<<dim3(64,4), blk, 0, stream>>>(X1B, WKV1B, bkv1, ws+oY1, 4096, 512, 256, 256);
  gather_kv<1,0><<<256, blk, 0, stream>>>(ws+oY1, pe1, ws+oK1P);
  gather_kv<1,1><<<256, blk, 0, stream>>>(ws+oY1, pe1, ws+oV1G);
  row_powernorm<<<1024, blk, 0, stream>>>(ws+oK1P, ws+oINVSP, 4096);
  kmkv<<<128, blk, 0, stream>>>(ws+oK1P, ws+oV1G, ws+oKM1, ws+oKV1M, 256);

  // ---- branch 2 staging ----
  gmfma<128,128,2,0,0><<<dim3(128,2), blk, 0, stream>>>(x, W2B, bsr2, ws+oX2, 16384, 256, 1024, 1024);
  ln_gelu_b<<<4096, blk, 0, stream>>>(ws+oX2, g2, b2, X2B, 16384);
  gmfma<128,128,0,1,0><<<dim3(128,4), blk, 0, stream>>>(X2B, WKV2B, bkv2, ws+oY2, 16384, 512, 256, 256);
  gather_kv<2,0><<<1024, blk, 0, stream>>>(ws+oY2, pe2, ws+oK2P);
  gather_kv<2,1><<<1024, blk, 0, stream>>>(ws+oY2, pe2, ws+oV2G);
  row_powernorm<<<4096, blk, 0, stream>>>(ws+oK2P, ws+oINVSP, 16384);
  kmkv<<<128, blk, 0, stream>>>(ws+oK2P, ws+oV2G, ws+oKM2, ws+oKV2M, 1024);

  // ---- attention (both branches) -> AB[b,t,0:512]; QBUF dead after ----
  attn_single<<<cB*128, blk, 0, stream>>>(ws+oQBUF, ws+oKM1, ws+oKV1M, AB, 0);
  attn_single<<<cB*128, blk, 0, stream>>>(ws+oQBUF, ws+oKM2, ws+oKV2M, AB, 256);

  // ---- interp + dwconv per branch (tmp image reuses QBUF) ----
  interp_img<1><<<16384, blk, 0, stream>>>(ws+oV1G, ws+oQBUF);
  dwconv_clean<<<cB*8*64, blk, 0, stream>>>(ws+oQBUF, Wdwc, bdwc, AB, 0);
  interp_img<2><<<16384, blk, 0, stream>>>(ws+oV2G, ws+oQBUF);
  dwconv_clean<<<cB*8*64, blk, 0, stream>>>(ws+oQBUF, Wdwc, bdwc, AB, 256);

  // ---- single fused projection: out = AB @ Wproj^T + bproj ----
  gmfma<128,128,0,1,0><<<dim3(512,2), blk, 0, stream>>>(AB, WPROJB, bproj, out, 65536, 256, 512, 512);
}